// Round 1
// baseline (1585.997 us; speedup 1.0000x reference)
//
#include <hip/hip_runtime.h>
#include <stdint.h>

typedef __attribute__((ext_vector_type(8))) short shortx8;
typedef __attribute__((ext_vector_type(4))) float floatx4;

#define NR 16384      // nodes (M and K of the big GEMM)
#define DD 256        // feature dim
#define SA 72         // LDS row stride in bf16 elems = 144 B (bank-conflict-free for b128 frag reads)
#define KCH 8192      // K per split-K chunk
#define BK 64         // K tile per iteration
#define NIT (KCH / BK)

__device__ __forceinline__ unsigned short f2bf(float f) {
    union { float f; uint32_t u; } v; v.f = f;
    uint32_t u = v.u;
    return (unsigned short)((u + 0x7FFFu + ((u >> 16) & 1u)) >> 16);
}

// ---------------------------------------------------------------------------
// Kernel 0: x [16384][256] f32  ->  xT [256][16384] bf16   (transpose+convert)
// ---------------------------------------------------------------------------
__global__ __launch_bounds__(256) void k_xpose(const float* __restrict__ x,
                                               unsigned short* __restrict__ xT) {
    __shared__ unsigned short t[64][72];
    const int kb = blockIdx.x * 64;   // k base (row of x)
    const int nb = blockIdx.y * 64;   // n base (col of x)
    const int tid = threadIdx.x;
    const int lr = tid >> 4;          // 0..15
    const int lc = (tid & 15) * 4;    // 0..60
#pragma unroll
    for (int i = 0; i < 4; ++i) {
        const int k = kb + lr + 16 * i;
        const float4 v = *(const float4*)(x + (size_t)k * DD + nb + lc);
        t[lc + 0][lr + 16 * i] = f2bf(v.x);
        t[lc + 1][lr + 16 * i] = f2bf(v.y);
        t[lc + 2][lr + 16 * i] = f2bf(v.z);
        t[lc + 3][lr + 16 * i] = f2bf(v.w);
    }
    __syncthreads();
#pragma unroll
    for (int i = 0; i < 4; ++i) {
        const int nl = lr + 16 * i;
        ushort4 o;
        o.x = t[nl][lc + 0]; o.y = t[nl][lc + 1];
        o.z = t[nl][lc + 2]; o.w = t[nl][lc + 3];
        *(ushort4*)(xT + (size_t)(nb + nl) * NR + kb + lc) = o;
    }
}

// ---------------------------------------------------------------------------
// Kernel 1: agg_sum partials = adj @ x   (and deg row-sums, fused)
// grid (256 m-tiles, 2 k-splits), 256 threads (4 waves)
// block tile: 64 rows x 256 cols, BK=64; wave tile 64x64 via 4x4 16x16x32 MFMA
// ---------------------------------------------------------------------------
__global__ __launch_bounds__(256, 2) void k_agg(const int* __restrict__ adj,
                                                const unsigned short* __restrict__ xT,
                                                float* __restrict__ aggP,
                                                float* __restrict__ degP) {
    __shared__ __align__(16) unsigned short As[64 * SA];    //  9216 B
    __shared__ __align__(16) unsigned short Bs[256 * SA];   // 36864 B
    __shared__ int degs[64];

    const int tid  = threadIdx.x;
    const int wave = tid >> 6;
    const int lane = tid & 63;
    const int q    = lane >> 4;       // quad 0..3
    const int ln   = lane & 15;
    const int m0   = blockIdx.x * 64;
    const int kb0  = blockIdx.y * KCH;

    if (tid < 64) degs[tid] = 0;

    const int arow = tid >> 4;          // 0..15
    const int acol = (tid & 15) * 4;    // 0..60

    // adj staging pointers: rows arow+{0,16,32,48}, cols acol..acol+3 (+k)
    const int* ap0 = adj + (size_t)(m0 + arow) * NR + kb0 + acol;
    const int* ap1 = ap0 + (size_t)16 * NR;
    const int* ap2 = ap0 + (size_t)32 * NR;
    const int* ap3 = ap0 + (size_t)48 * NR;

    // B staging: 2304 16B-chunks (256 rows x 9, chunk 8 = pad), 36 wave-instrs,
    // 9 per wave. Per-lane global src, wave-uniform LDS dst (+lane*16).
    const unsigned short* bg[9];
    unsigned short* const blb = Bs + wave * 9 * 512;  // 512 ushorts = 64 lanes*16B
#pragma unroll
    for (int j = 0; j < 9; ++j) {
        const int cid = (wave * 9 + j) * 64 + lane;
        const int n = cid / 9;
        int c = cid - n * 9; if (c > 7) c = 7;       // pad lane: harmless reload
        bg[j] = xT + (size_t)n * NR + kb0 + c * 8;
    }

    floatx4 acc[4][4] = {};
    int dacc0 = 0, dacc1 = 0, dacc2 = 0, dacc3 = 0;

    for (int it = 0; it < NIT; ++it) {
        __syncthreads();   // previous iteration's frag reads done

        // ---- stage B: xT -> LDS (direct-to-LDS, 16B/lane) ----
#pragma unroll
        for (int j = 0; j < 9; ++j) {
            __builtin_amdgcn_global_load_lds(
                (const __attribute__((address_space(1))) void*)bg[j],
                (__attribute__((address_space(3))) void*)(blb + j * 512),
                16, 0, 0);
            bg[j] += BK;
        }

        // ---- stage A: adj int32 -> bf16 {0,1.0}, fused deg accumulation ----
        const int4 a0 = *(const int4*)ap0; ap0 += BK;
        const int4 a1 = *(const int4*)ap1; ap1 += BK;
        const int4 a2 = *(const int4*)ap2; ap2 += BK;
        const int4 a3 = *(const int4*)ap3; ap3 += BK;

        ushort4 w;
        w.x = a0.x ? 0x3F80 : 0; w.y = a0.y ? 0x3F80 : 0;
        w.z = a0.z ? 0x3F80 : 0; w.w = a0.w ? 0x3F80 : 0;
        *(ushort4*)&As[(arow +  0) * SA + acol] = w;
        dacc0 += a0.x + a0.y + a0.z + a0.w;

        w.x = a1.x ? 0x3F80 : 0; w.y = a1.y ? 0x3F80 : 0;
        w.z = a1.z ? 0x3F80 : 0; w.w = a1.w ? 0x3F80 : 0;
        *(ushort4*)&As[(arow + 16) * SA + acol] = w;
        dacc1 += a1.x + a1.y + a1.z + a1.w;

        w.x = a2.x ? 0x3F80 : 0; w.y = a2.y ? 0x3F80 : 0;
        w.z = a2.z ? 0x3F80 : 0; w.w = a2.w ? 0x3F80 : 0;
        *(ushort4*)&As[(arow + 32) * SA + acol] = w;
        dacc2 += a2.x + a2.y + a2.z + a2.w;

        w.x = a3.x ? 0x3F80 : 0; w.y = a3.y ? 0x3F80 : 0;
        w.z = a3.z ? 0x3F80 : 0; w.w = a3.w ? 0x3F80 : 0;
        *(ushort4*)&As[(arow + 48) * SA + acol] = w;
        dacc3 += a3.x + a3.y + a3.z + a3.w;

        __syncthreads();   // staging visible (compiler drains vmcnt+lgkm)

        // ---- MFMA: 2 k-steps x 4x4 tiles ----
#pragma unroll
        for (int ks = 0; ks < 2; ++ks) {
            const int kk = ks * 32 + q * 8;
            shortx8 af[4], bf[4];
#pragma unroll
            for (int mt = 0; mt < 4; ++mt)
                af[mt] = *(const shortx8*)&As[(mt * 16 + ln) * SA + kk];
#pragma unroll
            for (int nt = 0; nt < 4; ++nt)
                bf[nt] = *(const shortx8*)&Bs[(wave * 64 + nt * 16 + ln) * SA + kk];
#pragma unroll
            for (int mt = 0; mt < 4; ++mt)
#pragma unroll
                for (int nt = 0; nt < 4; ++nt)
                    acc[mt][nt] = __builtin_amdgcn_mfma_f32_16x16x32_bf16(
                        af[mt], bf[nt], acc[mt][nt], 0, 0, 0);
        }
    }

    // ---- deg reduce + write ----
    atomicAdd(&degs[arow +  0], dacc0);
    atomicAdd(&degs[arow + 16], dacc1);
    atomicAdd(&degs[arow + 32], dacc2);
    atomicAdd(&degs[arow + 48], dacc3);
    __syncthreads();
    if (tid < 64) degP[(size_t)blockIdx.y * NR + m0 + tid] = (float)degs[tid];

    // ---- acc writeback (C/D layout: col=ln, row=q*4+r) ----
    float* const outb = aggP + (size_t)blockIdx.y * NR * DD;
#pragma unroll
    for (int mt = 0; mt < 4; ++mt)
#pragma unroll
        for (int nt = 0; nt < 4; ++nt)
#pragma unroll
            for (int r = 0; r < 4; ++r) {
                const int row = m0 + mt * 16 + q * 4 + r;
                const int col = wave * 64 + nt * 16 + ln;
                outb[(size_t)row * DD + col] = acc[mt][nt][r];
            }
}

// ---------------------------------------------------------------------------
// Kernel 2: out = ((p0+p1)/deg) @ W^T + b     M=16384, N=256, K=256
// grid 256 blocks x 256 threads; same wave tiling as k_agg, 4 K-iters
// ---------------------------------------------------------------------------
__global__ __launch_bounds__(256, 2) void k_lin(const float* __restrict__ aggP,
                                                const float* __restrict__ degP,
                                                const float* __restrict__ W,
                                                const float* __restrict__ bias,
                                                float* __restrict__ out) {
    __shared__ __align__(16) unsigned short As[64 * SA];
    __shared__ __align__(16) unsigned short Bs[256 * SA];
    __shared__ float rdeg[64];
    __shared__ float bsh[256];

    const int tid  = threadIdx.x;
    const int wave = tid >> 6;
    const int lane = tid & 63;
    const int q    = lane >> 4;
    const int ln   = lane & 15;
    const int m0   = blockIdx.x * 64;

    if (tid < 64) {
        const float d = degP[m0 + tid] + degP[NR + m0 + tid];
        rdeg[tid] = 1.0f / d;
    }
    bsh[tid] = bias[tid];

    const int arow = tid >> 4;
    const int acol = (tid & 15) * 4;

    floatx4 acc[4][4] = {};

    for (int it = 0; it < 4; ++it) {
        const int kb = it * 64;
        __syncthreads();

        // stage A: (p0+p1)*rdeg -> bf16
#pragma unroll
        for (int i = 0; i < 4; ++i) {
            const int r = arow + 16 * i;
            const size_t g = (size_t)(m0 + r) * DD + kb + acol;
            const float4 p0 = *(const float4*)(aggP + g);
            const float4 p1 = *(const float4*)(aggP + (size_t)NR * DD + g);
            const float s = rdeg[r];
            ushort4 o;
            o.x = f2bf((p0.x + p1.x) * s);
            o.y = f2bf((p0.y + p1.y) * s);
            o.z = f2bf((p0.z + p1.z) * s);
            o.w = f2bf((p0.w + p1.w) * s);
            *(ushort4*)&As[r * SA + acol] = o;
        }
        // stage B: W rows (out-col major = B[n][k] natural) -> bf16
#pragma unroll
        for (int i = 0; i < 16; ++i) {
            const int r = arow + 16 * i;
            const float4 w4 = *(const float4*)(W + (size_t)r * DD + kb + acol);
            ushort4 o;
            o.x = f2bf(w4.x); o.y = f2bf(w4.y);
            o.z = f2bf(w4.z); o.w = f2bf(w4.w);
            *(ushort4*)&Bs[r * SA + acol] = o;
        }
        __syncthreads();

#pragma unroll
        for (int ks = 0; ks < 2; ++ks) {
            const int kk = ks * 32 + q * 8;
            shortx8 af[4], bf[4];
#pragma unroll
            for (int mt = 0; mt < 4; ++mt)
                af[mt] = *(const shortx8*)&As[(mt * 16 + ln) * SA + kk];
#pragma unroll
            for (int nt = 0; nt < 4; ++nt)
                bf[nt] = *(const shortx8*)&Bs[(wave * 64 + nt * 16 + ln) * SA + kk];
#pragma unroll
            for (int mt = 0; mt < 4; ++mt)
#pragma unroll
                for (int nt = 0; nt < 4; ++nt)
                    acc[mt][nt] = __builtin_amdgcn_mfma_f32_16x16x32_bf16(
                        af[mt], bf[nt], acc[mt][nt], 0, 0, 0);
        }
    }

#pragma unroll
    for (int mt = 0; mt < 4; ++mt)
#pragma unroll
        for (int nt = 0; nt < 4; ++nt)
#pragma unroll
            for (int r = 0; r < 4; ++r) {
                const int row = m0 + mt * 16 + q * 4 + r;
                const int col = wave * 64 + nt * 16 + ln;
                out[(size_t)row * DD + col] = acc[mt][nt][r] + bsh[col];
            }
}

// ---------------------------------------------------------------------------
extern "C" void kernel_launch(void* const* d_in, const int* in_sizes, int n_in,
                              void* d_out, int out_size, void* d_ws, size_t ws_size,
                              hipStream_t stream) {
    const float* x    = (const float*)d_in[0];
    const int*   adj  = (const int*)d_in[1];
    const float* W    = (const float*)d_in[2];
    const float* bias = (const float*)d_in[3];
    float* out = (float*)d_out;

    // ws layout: xT bf16 8 MB | aggP fp32 2x16 MB | degP fp32 2x64 KB
    unsigned short* xT  = (unsigned short*)d_ws;
    float* aggP = (float*)((char*)d_ws + (size_t)8 * 1024 * 1024);
    float* degP = (float*)((char*)d_ws + (size_t)40 * 1024 * 1024);

    k_xpose<<<dim3(NR / 64, DD / 64), 256, 0, stream>>>(x, xT);
    k_agg<<<dim3(NR / 64, 2), 256, 0, stream>>>(adj, xT, aggP, degP);
    k_lin<<<dim3(NR / 64), 256, 0, stream>>>(aggP, degP, W, bias, out);
}

// Round 2
// 1528.440 us; speedup vs baseline: 1.0377x; 1.0377x over previous
//
#include <hip/hip_runtime.h>
#include <stdint.h>

typedef __attribute__((ext_vector_type(8))) short shortx8;
typedef __attribute__((ext_vector_type(4))) float floatx4;

#define NR 16384      // nodes (M and K of the big GEMM)
#define DD 256        // feature dim
#define SA 72         // LDS row stride in bf16 elems = 144 B
#define NSPLIT 4      // split-K factor
#define KCH (NR / NSPLIT)
#define BK 64         // K tile per iteration
#define NIT (KCH / BK)

__device__ __forceinline__ unsigned short f2bf(float f) {
    union { float f; uint32_t u; } v; v.f = f;
    uint32_t u = v.u;
    return (unsigned short)((u + 0x7FFFu + ((u >> 16) & 1u)) >> 16);
}

// ---------------------------------------------------------------------------
// Kernel 0: x [16384][256] f32  ->  xT [256][16384] bf16   (transpose+convert)
// ---------------------------------------------------------------------------
__global__ __launch_bounds__(256) void k_xpose(const float* __restrict__ x,
                                               unsigned short* __restrict__ xT) {
    __shared__ unsigned short t[64][72];
    const int kb = blockIdx.x * 64;   // k base (row of x)
    const int nb = blockIdx.y * 64;   // n base (col of x)
    const int tid = threadIdx.x;
    const int lr = tid >> 4;          // 0..15
    const int lc = (tid & 15) * 4;    // 0..60
#pragma unroll
    for (int i = 0; i < 4; ++i) {
        const int k = kb + lr + 16 * i;
        const float4 v = *(const float4*)(x + (size_t)k * DD + nb + lc);
        t[lc + 0][lr + 16 * i] = f2bf(v.x);
        t[lc + 1][lr + 16 * i] = f2bf(v.y);
        t[lc + 2][lr + 16 * i] = f2bf(v.z);
        t[lc + 3][lr + 16 * i] = f2bf(v.w);
    }
    __syncthreads();
#pragma unroll
    for (int i = 0; i < 4; ++i) {
        const int nl = lr + 16 * i;
        ushort4 o;
        o.x = t[nl][lc + 0]; o.y = t[nl][lc + 1];
        o.z = t[nl][lc + 2]; o.w = t[nl][lc + 3];
        *(ushort4*)(xT + (size_t)(nb + nl) * NR + kb + lc) = o;
    }
}

// ---------------------------------------------------------------------------
// Kernel 1: agg_sum partials = adj @ x   (and deg row-sums, fused)
// grid (256 m-tiles, NSPLIT k-splits), 256 threads (4 waves), 3 blocks/CU
// block tile: 64 rows x 256 cols, BK=64; wave tile 64x64 via 4x4 16x16x32 MFMA
// adj loads register-prefetched one iteration ahead so the per-barrier
// vmcnt(0) drain only pays L2 latency (B staging), not adj's HBM latency.
// ---------------------------------------------------------------------------
__global__ __launch_bounds__(256, 3) void k_agg(const int* __restrict__ adj,
                                                const unsigned short* __restrict__ xT,
                                                float* __restrict__ aggP,
                                                float* __restrict__ degP) {
    __shared__ __align__(16) unsigned short As[64 * SA];    //  9216 B
    __shared__ __align__(16) unsigned short Bs[256 * SA];   // 36864 B
    __shared__ int degs[64];

    const int tid  = threadIdx.x;
    const int wave = tid >> 6;
    const int lane = tid & 63;
    const int q    = lane >> 4;       // quad 0..3
    const int ln   = lane & 15;
    const int m0   = blockIdx.x * 64;
    const int kb0  = blockIdx.y * KCH;

    if (tid < 64) degs[tid] = 0;

    const int arow = tid >> 4;          // 0..15
    const int acol = (tid & 15) * 4;    // 0..60

    // adj staging pointers: rows arow+{0,16,32,48}, cols acol..acol+3 (+k)
    const int* ap0 = adj + (size_t)(m0 + arow) * NR + kb0 + acol;
    const int* ap1 = ap0 + (size_t)16 * NR;
    const int* ap2 = ap0 + (size_t)32 * NR;
    const int* ap3 = ap0 + (size_t)48 * NR;

    // B staging: 64 rows/wave x 9 chunks (chunk 8 = pad) = 9 wave-instrs.
    const unsigned short* bg[9];
    unsigned short* const blb = Bs + wave * 9 * 512;  // 512 ushorts = 64 lanes*16B
#pragma unroll
    for (int j = 0; j < 9; ++j) {
        const int cid = (wave * 9 + j) * 64 + lane;
        const int n = cid / 9;
        int c = cid - n * 9; if (c > 7) c = 7;       // pad lane: harmless reload
        bg[j] = xT + (size_t)n * NR + kb0 + c * 8;
    }

    floatx4 acc[4][4] = {};
    int dacc0 = 0, dacc1 = 0, dacc2 = 0, dacc3 = 0;

    // ---- prologue: prefetch adj for iteration 0 ----
    int4 a0 = *(const int4*)ap0;
    int4 a1 = *(const int4*)ap1;
    int4 a2 = *(const int4*)ap2;
    int4 a3 = *(const int4*)ap3;

    for (int it = 0; it < NIT; ++it) {
        __syncthreads();   // barrier 1: previous iteration's frag reads done
                           // (adj prefetch issued ~1 MFMA-phase ago: drain ~free)

        // ---- stage B: xT -> LDS (direct-to-LDS, 16B/lane) ----
#pragma unroll
        for (int j = 0; j < 9; ++j) {
            __builtin_amdgcn_global_load_lds(
                (const __attribute__((address_space(1))) void*)bg[j],
                (__attribute__((address_space(3))) void*)(blb + j * 512),
                16, 0, 0);
            bg[j] += BK;
        }

        // ---- write As from prefetched adj regs, fused deg accumulation ----
        ushort4 w;
        w.x = a0.x ? 0x3F80 : 0; w.y = a0.y ? 0x3F80 : 0;
        w.z = a0.z ? 0x3F80 : 0; w.w = a0.w ? 0x3F80 : 0;
        *(ushort4*)&As[(arow +  0) * SA + acol] = w;
        dacc0 += a0.x + a0.y + a0.z + a0.w;

        w.x = a1.x ? 0x3F80 : 0; w.y = a1.y ? 0x3F80 : 0;
        w.z = a1.z ? 0x3F80 : 0; w.w = a1.w ? 0x3F80 : 0;
        *(ushort4*)&As[(arow + 16) * SA + acol] = w;
        dacc1 += a1.x + a1.y + a1.z + a1.w;

        w.x = a2.x ? 0x3F80 : 0; w.y = a2.y ? 0x3F80 : 0;
        w.z = a2.z ? 0x3F80 : 0; w.w = a2.w ? 0x3F80 : 0;
        *(ushort4*)&As[(arow + 32) * SA + acol] = w;
        dacc2 += a2.x + a2.y + a2.z + a2.w;

        w.x = a3.x ? 0x3F80 : 0; w.y = a3.y ? 0x3F80 : 0;
        w.z = a3.z ? 0x3F80 : 0; w.w = a3.w ? 0x3F80 : 0;
        *(ushort4*)&As[(arow + 48) * SA + acol] = w;
        dacc3 += a3.x + a3.y + a3.z + a3.w;

        __syncthreads();   // barrier 2: staging visible (drain = B's L2 latency)

        // ---- prefetch adj for it+1 (flies during the MFMA phase) ----
        if (it + 1 < NIT) {
            ap0 += BK; ap1 += BK; ap2 += BK; ap3 += BK;
            a0 = *(const int4*)ap0;
            a1 = *(const int4*)ap1;
            a2 = *(const int4*)ap2;
            a3 = *(const int4*)ap3;
        }

        // ---- MFMA: 2 k-steps x 4x4 tiles ----
#pragma unroll
        for (int ks = 0; ks < 2; ++ks) {
            const int kk = ks * 32 + q * 8;
            shortx8 af[4], bf[4];
#pragma unroll
            for (int mt = 0; mt < 4; ++mt)
                af[mt] = *(const shortx8*)&As[(mt * 16 + ln) * SA + kk];
#pragma unroll
            for (int nt = 0; nt < 4; ++nt)
                bf[nt] = *(const shortx8*)&Bs[(wave * 64 + nt * 16 + ln) * SA + kk];
#pragma unroll
            for (int mt = 0; mt < 4; ++mt)
#pragma unroll
                for (int nt = 0; nt < 4; ++nt)
                    acc[mt][nt] = __builtin_amdgcn_mfma_f32_16x16x32_bf16(
                        af[mt], bf[nt], acc[mt][nt], 0, 0, 0);
        }
    }

    // ---- deg reduce + write ----
    atomicAdd(&degs[arow +  0], dacc0);
    atomicAdd(&degs[arow + 16], dacc1);
    atomicAdd(&degs[arow + 32], dacc2);
    atomicAdd(&degs[arow + 48], dacc3);
    __syncthreads();
    if (tid < 64) degP[(size_t)blockIdx.y * NR + m0 + tid] = (float)degs[tid];

    // ---- acc writeback (C/D layout: col=ln, row=q*4+r) ----
    float* const outb = aggP + (size_t)blockIdx.y * NR * DD;
#pragma unroll
    for (int mt = 0; mt < 4; ++mt)
#pragma unroll
        for (int nt = 0; nt < 4; ++nt)
#pragma unroll
            for (int r = 0; r < 4; ++r) {
                const int row = m0 + mt * 16 + q * 4 + r;
                const int col = wave * 64 + nt * 16 + ln;
                outb[(size_t)row * DD + col] = acc[mt][nt][r];
            }
}

// ---------------------------------------------------------------------------
// Kernel 2: out = ((p0+p1+p2+p3)/deg) @ W^T + b    M=16384, N=256, K=256
// ---------------------------------------------------------------------------
__global__ __launch_bounds__(256, 2) void k_lin(const float* __restrict__ aggP,
                                                const float* __restrict__ degP,
                                                const float* __restrict__ W,
                                                const float* __restrict__ bias,
                                                float* __restrict__ out) {
    __shared__ __align__(16) unsigned short As[64 * SA];
    __shared__ __align__(16) unsigned short Bs[256 * SA];
    __shared__ float rdeg[64];
    __shared__ float bsh[256];

    const int tid  = threadIdx.x;
    const int wave = tid >> 6;
    const int lane = tid & 63;
    const int q    = lane >> 4;
    const int ln   = lane & 15;
    const int m0   = blockIdx.x * 64;

    if (tid < 64) {
        float d = 0.f;
#pragma unroll
        for (int s = 0; s < NSPLIT; ++s) d += degP[(size_t)s * NR + m0 + tid];
        rdeg[tid] = 1.0f / d;
    }
    bsh[tid] = bias[tid];

    const int arow = tid >> 4;
    const int acol = (tid & 15) * 4;

    floatx4 acc[4][4] = {};

    for (int it = 0; it < 4; ++it) {
        const int kb = it * 64;
        __syncthreads();

        // stage A: (sum of partials)*rdeg -> bf16
#pragma unroll
        for (int i = 0; i < 4; ++i) {
            const int r = arow + 16 * i;
            const size_t g = (size_t)(m0 + r) * DD + kb + acol;
            float4 p = *(const float4*)(aggP + g);
#pragma unroll
            for (int s = 1; s < NSPLIT; ++s) {
                const float4 ps = *(const float4*)(aggP + (size_t)s * NR * DD + g);
                p.x += ps.x; p.y += ps.y; p.z += ps.z; p.w += ps.w;
            }
            const float sc = rdeg[r];
            ushort4 o;
            o.x = f2bf(p.x * sc);
            o.y = f2bf(p.y * sc);
            o.z = f2bf(p.z * sc);
            o.w = f2bf(p.w * sc);
            *(ushort4*)&As[r * SA + acol] = o;
        }
        // stage B: W rows (out-col major = B[n][k] natural) -> bf16
#pragma unroll
        for (int i = 0; i < 16; ++i) {
            const int r = arow + 16 * i;
            const float4 w4 = *(const float4*)(W + (size_t)r * DD + kb + acol);
            ushort4 o;
            o.x = f2bf(w4.x); o.y = f2bf(w4.y);
            o.z = f2bf(w4.z); o.w = f2bf(w4.w);
            *(ushort4*)&Bs[r * SA + acol] = o;
        }
        __syncthreads();

#pragma unroll
        for (int ks = 0; ks < 2; ++ks) {
            const int kk = ks * 32 + q * 8;
            shortx8 af[4], bf[4];
#pragma unroll
            for (int mt = 0; mt < 4; ++mt)
                af[mt] = *(const shortx8*)&As[(mt * 16 + ln) * SA + kk];
#pragma unroll
            for (int nt = 0; nt < 4; ++nt)
                bf[nt] = *(const shortx8*)&Bs[(wave * 64 + nt * 16 + ln) * SA + kk];
#pragma unroll
            for (int mt = 0; mt < 4; ++mt)
#pragma unroll
                for (int nt = 0; nt < 4; ++nt)
                    acc[mt][nt] = __builtin_amdgcn_mfma_f32_16x16x32_bf16(
                        af[mt], bf[nt], acc[mt][nt], 0, 0, 0);
        }
    }

#pragma unroll
    for (int mt = 0; mt < 4; ++mt)
#pragma unroll
        for (int nt = 0; nt < 4; ++nt)
#pragma unroll
            for (int r = 0; r < 4; ++r) {
                const int row = m0 + mt * 16 + q * 4 + r;
                const int col = wave * 64 + nt * 16 + ln;
                out[(size_t)row * DD + col] = acc[mt][nt][r] + bsh[col];
            }
}

// ---------------------------------------------------------------------------
extern "C" void kernel_launch(void* const* d_in, const int* in_sizes, int n_in,
                              void* d_out, int out_size, void* d_ws, size_t ws_size,
                              hipStream_t stream) {
    const float* x    = (const float*)d_in[0];
    const int*   adj  = (const int*)d_in[1];
    const float* W    = (const float*)d_in[2];
    const float* bias = (const float*)d_in[3];
    float* out = (float*)d_out;

    // ws layout: xT bf16 8 MB | aggP fp32 NSPLIT x 16 MB | degP fp32 NSPLIT x 64 KB
    unsigned short* xT  = (unsigned short*)d_ws;
    float* aggP = (float*)((char*)d_ws + (size_t)8 * 1024 * 1024);
    float* degP = (float*)((char*)d_ws + (size_t)(8 + 16 * NSPLIT) * 1024 * 1024);

    k_xpose<<<dim3(NR / 64, DD / 64), 256, 0, stream>>>(x, xT);
    k_agg<<<dim3(NR / 64, NSPLIT), 256, 0, stream>>>(adj, xT, aggP, degP);
    k_lin<<<dim3(NR / 64), 256, 0, stream>>>(aggP, degP, W, bias, out);
}